// Round 3
// baseline (1786.194 us; speedup 1.0000x reference)
//
#include <hip/hip_runtime.h>

// GCN encoder: 2x GCNConv (symmetric norm, self-loops) + global mean pool.
// N=100000 nodes, E=1600000 edges, F_IN=64, H=128, O=64, B=64 graphs.
//
// Algebraic restructure:
//   layer1: h1 = relu((A x) W1 + b1)         (aggregate 64-wide x, then GEMM)
//   layer2+pool: out[b] = (1/cnt[b]) * sum_{edges e: batch[dst]=b} h2[src]*norm + b2
//            where h2 = h1 W2                 (pool fused into edge pass)

#define NN 100000
#define NE 1600000
#define FI 64
#define FH 128
#define FO 64
#define NB 64

// ---------------- init: deg=1 (self-loop), zero pooled sums/counts ----------
__global__ __launch_bounds__(256) void k_init(float* __restrict__ deg,
                                              float* __restrict__ out_sums,
                                              float* __restrict__ cnts) {
  int i = blockIdx.x * 256 + threadIdx.x;
  if (i < NN) deg[i] = 1.0f;
  if (i < NB * FO) out_sums[i] = 0.0f;
  if (i < NB) cnts[i] = 0.0f;
}

// ---------------- degree count over dst -------------------------------------
__global__ __launch_bounds__(256) void k_deg(const int* __restrict__ dst,
                                             float* __restrict__ deg) {
  int stride = gridDim.x * 256;
  for (int e = blockIdx.x * 256 + threadIdx.x; e < NE; e += stride)
    atomicAdd(&deg[dst[e]], 1.0f);
}

// ---------------- dinv = rsqrt(deg)  (deg >= 1 always, self-loop) -----------
__global__ __launch_bounds__(256) void k_dinv(float* __restrict__ deg) {
  int i = blockIdx.x * 256 + threadIdx.x;
  if (i < NN) deg[i] = rsqrtf(deg[i]);
}

// ---------------- aggx init with self-loop: aggx[i] = x[i]*dinv[i]^2 --------
__global__ __launch_bounds__(256) void k_aggx_init(const float* __restrict__ x,
                                                   const float* __restrict__ dinv,
                                                   float* __restrict__ aggx) {
  int i = blockIdx.x * 256 + threadIdx.x;  // float4 index
  if (i < NN * (FI / 4)) {
    int node = i >> 4;  // FI/4 = 16 float4 per row
    float di = dinv[node];
    float s = di * di;
    float4 v = ((const float4*)x)[i];
    v.x *= s; v.y *= s; v.z *= s; v.w *= s;
    ((float4*)aggx)[i] = v;
  }
}

// ---------------- edge scatter: aggx[dst] += x[src]*norm  (wave per edge) ---
__global__ __launch_bounds__(256) void k_aggx_edges(const int* __restrict__ es,
                                                    const int* __restrict__ ed,
                                                    const float* __restrict__ dinv,
                                                    const float* __restrict__ x,
                                                    float* __restrict__ aggx) {
  int lane = threadIdx.x & 63;
  int wid = (blockIdx.x * 256 + threadIdx.x) >> 6;
  int nw = (gridDim.x * 256) >> 6;
  for (int e = wid; e < NE; e += nw) {
    int e0 = __builtin_amdgcn_readfirstlane(e);  // wave-uniform -> s_load path
    int s = es[e0];
    int d = ed[e0];
    float nrm = dinv[s] * dinv[d];
    atomicAdd(&aggx[d * FI + lane], x[s * FI + lane] * nrm);
  }
}

// ---------------- GEMM1: h1 = relu(aggx @ W1 + b1)   [N,64]@[64,128] --------
// block: 64 rows x 128 cols, 256 threads, thread tile 4x8
__global__ __launch_bounds__(256) void k_gemm1(const float* __restrict__ X,
                                               const float* __restrict__ W,
                                               const float* __restrict__ bias,
                                               float* __restrict__ Y) {
  __shared__ float XsT[FI][64];   // [k][r] transposed, 16KB
  __shared__ float Ws[FI][FH];    // 32KB
  int tid = threadIdx.x;
  int row0 = blockIdx.x * 64;

  for (int i = tid; i < FI * FH / 4; i += 256)
    ((float4*)&Ws[0][0])[i] = ((const float4*)W)[i];

  for (int i = tid; i < 64 * (FI / 4); i += 256) {  // 1024 float4 loads
    int c4 = i & 15;          // coalesced along the row
    int r = i >> 4;
    int row = row0 + r;
    float4 v = (row < NN) ? ((const float4*)X)[row * (FI / 4) + c4]
                          : make_float4(0.f, 0.f, 0.f, 0.f);
    XsT[c4 * 4 + 0][r] = v.x; XsT[c4 * 4 + 1][r] = v.y;
    XsT[c4 * 4 + 2][r] = v.z; XsT[c4 * 4 + 3][r] = v.w;
  }
  __syncthreads();

  int tr = tid & 15;   // row group: rows tr*4..+3
  int tc = tid >> 4;   // col group: cols tc*8..+7
  float acc[4][8];
#pragma unroll
  for (int i = 0; i < 4; i++)
#pragma unroll
    for (int j = 0; j < 8; j++) acc[i][j] = 0.f;

#pragma unroll 8
  for (int k = 0; k < FI; k++) {
    float4 a = *(const float4*)&XsT[k][tr * 4];
    float4 w0 = *(const float4*)&Ws[k][tc * 8];
    float4 w1 = *(const float4*)&Ws[k][tc * 8 + 4];
    float av[4] = {a.x, a.y, a.z, a.w};
    float wv[8] = {w0.x, w0.y, w0.z, w0.w, w1.x, w1.y, w1.z, w1.w};
#pragma unroll
    for (int i = 0; i < 4; i++)
#pragma unroll
      for (int j = 0; j < 8; j++) acc[i][j] += av[i] * wv[j];
  }

  float4 bv0 = *(const float4*)&bias[tc * 8];
  float4 bv1 = *(const float4*)&bias[tc * 8 + 4];
  float bb[8] = {bv0.x, bv0.y, bv0.z, bv0.w, bv1.x, bv1.y, bv1.z, bv1.w};
#pragma unroll
  for (int i = 0; i < 4; i++) {
    int row = row0 + tr * 4 + i;
    if (row < NN) {
      float o[8];
#pragma unroll
      for (int j = 0; j < 8; j++) {
        float v = acc[i][j] + bb[j];
        o[j] = v > 0.f ? v : 0.f;
      }
      float4* dst = (float4*)&Y[row * FH + tc * 8];
      dst[0] = make_float4(o[0], o[1], o[2], o[3]);
      dst[1] = make_float4(o[4], o[5], o[6], o[7]);
    }
  }
}

// ---------------- GEMM2: h2 = h1 @ W2   [N,128]@[128,64] (no bias) ----------
// block: 64 rows x 64 cols, 256 threads, thread tile 4x4
__global__ __launch_bounds__(256) void k_gemm2(const float* __restrict__ X,
                                               const float* __restrict__ W,
                                               float* __restrict__ Y) {
  __shared__ float XsT[FH][64];   // 32KB
  __shared__ float Ws[FH][FO];    // 32KB -> total exactly 64KB
  int tid = threadIdx.x;
  int row0 = blockIdx.x * 64;

  for (int i = tid; i < FH * FO / 4; i += 256)
    ((float4*)&Ws[0][0])[i] = ((const float4*)W)[i];

  for (int i = tid; i < 64 * (FH / 4); i += 256) {  // 2048 float4 loads
    int c4 = i & 31;          // coalesced along the row
    int r = i >> 5;
    int row = row0 + r;
    float4 v = (row < NN) ? ((const float4*)X)[row * (FH / 4) + c4]
                          : make_float4(0.f, 0.f, 0.f, 0.f);
    XsT[c4 * 4 + 0][r] = v.x; XsT[c4 * 4 + 1][r] = v.y;
    XsT[c4 * 4 + 2][r] = v.z; XsT[c4 * 4 + 3][r] = v.w;
  }
  __syncthreads();

  int tr = tid & 15;   // rows tr*4..+3
  int tc = tid >> 4;   // cols tc*4..+3
  float acc[4][4];
#pragma unroll
  for (int i = 0; i < 4; i++)
#pragma unroll
    for (int j = 0; j < 4; j++) acc[i][j] = 0.f;

#pragma unroll 8
  for (int k = 0; k < FH; k++) {
    float4 a = *(const float4*)&XsT[k][tr * 4];
    float4 w = *(const float4*)&Ws[k][tc * 4];
    float av[4] = {a.x, a.y, a.z, a.w};
    float wv[4] = {w.x, w.y, w.z, w.w};
#pragma unroll
    for (int i = 0; i < 4; i++)
#pragma unroll
      for (int j = 0; j < 4; j++) acc[i][j] += av[i] * wv[j];
  }

#pragma unroll
  for (int i = 0; i < 4; i++) {
    int row = row0 + tr * 4 + i;
    if (row < NN) {
      *(float4*)&Y[row * FO + tc * 4] =
          make_float4(acc[i][0], acc[i][1], acc[i][2], acc[i][3]);
    }
  }
}

// ---------------- node counts per graph -------------------------------------
__global__ __launch_bounds__(256) void k_cnt(const int* __restrict__ batch,
                                             float* __restrict__ cnts) {
  int i = blockIdx.x * 256 + threadIdx.x;
  if (i < NN) atomicAdd(&cnts[batch[i]], 1.0f);
}

// ---------------- layer2 aggregation fused with pooling ---------------------
// out_sums[batch[dst]] += h2[src]*norm over all edges + self-loops.
// LDS accumulator [64 graphs x 64 feats] per block, merged atomically.
__global__ __launch_bounds__(256) void k_out_edges(const int* __restrict__ es,
                                                   const int* __restrict__ ed,
                                                   const int* __restrict__ batch,
                                                   const float* __restrict__ dinv,
                                                   const float* __restrict__ h2,
                                                   float* __restrict__ out_sums) {
  __shared__ float lds[NB * FO];  // 16KB
  for (int i = threadIdx.x; i < NB * FO; i += 256) lds[i] = 0.f;
  __syncthreads();

  int lane = threadIdx.x & 63;
  int wid = (blockIdx.x * 256 + threadIdx.x) >> 6;
  int nw = (gridDim.x * 256) >> 6;
  const int total = NE + NN;  // real edges + self-loops
  for (int e = wid; e < total; e += nw) {
    int e0 = __builtin_amdgcn_readfirstlane(e);
    int s, d;
    float nrm;
    if (e0 < NE) {
      s = es[e0];
      d = ed[e0];
      nrm = dinv[s] * dinv[d];
    } else {
      s = e0 - NE;
      d = s;
      float di = dinv[s];
      nrm = di * di;
    }
    int b = batch[d];
    atomicAdd(&lds[b * FO + lane], h2[s * FO + lane] * nrm);
  }
  __syncthreads();
  for (int i = threadIdx.x; i < NB * FO; i += 256) {
    float v = lds[i];
    if (v != 0.f) atomicAdd(&out_sums[i], v);
  }
}

// ---------------- final: mean + bias ----------------------------------------
__global__ __launch_bounds__(256) void k_final(const float* __restrict__ out_sums,
                                               const float* __restrict__ cnts,
                                               const float* __restrict__ b2,
                                               float* __restrict__ out) {
  int i = blockIdx.x * 256 + threadIdx.x;
  if (i < NB * FO) {
    int b = i >> 6, j = i & 63;
    out[i] = out_sums[i] / fmaxf(cnts[b], 1.0f) + b2[j];
  }
}

extern "C" void kernel_launch(void* const* d_in, const int* in_sizes, int n_in,
                              void* d_out, int out_size, void* d_ws, size_t ws_size,
                              hipStream_t stream) {
  const float* x = (const float*)d_in[0];
  const int* ei = (const int*)d_in[1];     // [2,E] int32
  const int* batch = (const int*)d_in[2];  // [N] int32
  const float* W1 = (const float*)d_in[3];
  const float* b1 = (const float*)d_in[4];
  const float* W2 = (const float*)d_in[5];
  const float* b2 = (const float*)d_in[6];
  float* out = (float*)d_out;

  const int* es = ei;       // edge_index[0] = src
  const int* ed = ei + NE;  // edge_index[1] = dst

  // workspace layout (f32): deg/dinv | aggx (reused as h2) | h1 | out_sums | cnts
  float* deg = (float*)d_ws;            // N (in-place -> dinv)
  float* aggx = deg + 100032;           // N*64  (25.6MB)
  float* h1 = aggx + (size_t)NN * FI;   // N*128 (51.2MB)
  float* out_sums = h1 + (size_t)NN * FH;
  float* cnts = out_sums + NB * FO;
  float* h2 = aggx;                     // aggx dead after gemm1

  k_init<<<(NN + 255) / 256, 256, 0, stream>>>(deg, out_sums, cnts);
  k_deg<<<1024, 256, 0, stream>>>(ed, deg);
  k_dinv<<<(NN + 255) / 256, 256, 0, stream>>>(deg);
  k_aggx_init<<<(NN * (FI / 4) + 255) / 256, 256, 0, stream>>>(x, deg, aggx);
  k_aggx_edges<<<2048, 256, 0, stream>>>(es, ed, deg, x, aggx);
  k_gemm1<<<(NN + 63) / 64, 256, 0, stream>>>(aggx, W1, b1, h1);
  k_gemm2<<<(NN + 63) / 64, 256, 0, stream>>>(h1, W2, h2);
  k_cnt<<<(NN + 255) / 256, 256, 0, stream>>>(batch, cnts);
  k_out_edges<<<1024, 256, 0, stream>>>(es, ed, batch, deg, h2, out_sums);
  k_final<<<16, 256, 0, stream>>>(out_sums, cnts, b2, out);
}

// Round 4
// 1162.608 us; speedup vs baseline: 1.5364x; 1.5364x over previous
//
#include <hip/hip_runtime.h>

// GCN encoder: 2x GCNConv (symmetric norm, self-loops) + global mean pool.
// N=100000 nodes, E=1600000 edges, F_IN=64, H=128, O=64, B=64 graphs.
//
// Algebraic restructure:
//   layer1: h1 = relu((A x) W1 + b1)         (aggregate 64-wide x, then GEMM)
//   layer2+pool: out[b] = (1/cnt[b]) * sum_{edges e: batch[dst]=b} h2[src]*norm + b2
//            where h2 = h1 W2                 (pool fused into edge pass)
//
// R3 fix: k_cnt (640us, 36% of total!) was 100K same-address f32 atomics on 64
// sorted buckets -> serialized RMW storm. batch is SORTED, so counts are
// segment lengths: cnts[b] = lb(b+1) - lb(b) via binary search. No atomics.

#define NN 100000
#define NE 1600000
#define FI 64
#define FH 128
#define FO 64
#define NB 64

// ---------------- init: deg=1 (self-loop), zero pooled sums ----------------
__global__ __launch_bounds__(256) void k_init(float* __restrict__ deg,
                                              float* __restrict__ out_sums) {
  int i = blockIdx.x * 256 + threadIdx.x;
  if (i < NN) deg[i] = 1.0f;
  if (i < NB * FO) out_sums[i] = 0.0f;
}

// ---------------- degree count over dst -------------------------------------
__global__ __launch_bounds__(256) void k_deg(const int* __restrict__ dst,
                                             float* __restrict__ deg) {
  int stride = gridDim.x * 256;
  for (int e = blockIdx.x * 256 + threadIdx.x; e < NE; e += stride)
    atomicAdd(&deg[dst[e]], 1.0f);
}

// ---------------- dinv = rsqrt(deg)  (deg >= 1 always, self-loop) -----------
__global__ __launch_bounds__(256) void k_dinv(float* __restrict__ deg) {
  int i = blockIdx.x * 256 + threadIdx.x;
  if (i < NN) deg[i] = rsqrtf(deg[i]);
}

// ---------------- aggx init with self-loop: aggx[i] = x[i]*dinv[i]^2 --------
__global__ __launch_bounds__(256) void k_aggx_init(const float* __restrict__ x,
                                                   const float* __restrict__ dinv,
                                                   float* __restrict__ aggx) {
  int i = blockIdx.x * 256 + threadIdx.x;  // float4 index
  if (i < NN * (FI / 4)) {
    int node = i >> 4;  // FI/4 = 16 float4 per row
    float di = dinv[node];
    float s = di * di;
    float4 v = ((const float4*)x)[i];
    v.x *= s; v.y *= s; v.z *= s; v.w *= s;
    ((float4*)aggx)[i] = v;
  }
}

// ---------------- edge scatter: aggx[dst] += x[src]*norm  (wave per edge) ---
__global__ __launch_bounds__(256) void k_aggx_edges(const int* __restrict__ es,
                                                    const int* __restrict__ ed,
                                                    const float* __restrict__ dinv,
                                                    const float* __restrict__ x,
                                                    float* __restrict__ aggx) {
  int lane = threadIdx.x & 63;
  int wid = (blockIdx.x * 256 + threadIdx.x) >> 6;
  int nw = (gridDim.x * 256) >> 6;
  for (int e = wid; e < NE; e += nw) {
    int e0 = __builtin_amdgcn_readfirstlane(e);  // wave-uniform -> s_load path
    int s = es[e0];
    int d = ed[e0];
    float nrm = dinv[s] * dinv[d];
    atomicAdd(&aggx[d * FI + lane], x[s * FI + lane] * nrm);
  }
}

// ---------------- GEMM1: h1 = relu(aggx @ W1 + b1)   [N,64]@[64,128] --------
// block: 64 rows x 128 cols, 256 threads, thread tile 4x8
__global__ __launch_bounds__(256) void k_gemm1(const float* __restrict__ X,
                                               const float* __restrict__ W,
                                               const float* __restrict__ bias,
                                               float* __restrict__ Y) {
  __shared__ float XsT[FI][64];   // [k][r] transposed, 16KB
  __shared__ float Ws[FI][FH];    // 32KB
  int tid = threadIdx.x;
  int row0 = blockIdx.x * 64;

  for (int i = tid; i < FI * FH / 4; i += 256)
    ((float4*)&Ws[0][0])[i] = ((const float4*)W)[i];

  for (int i = tid; i < 64 * (FI / 4); i += 256) {  // 1024 float4 loads
    int c4 = i & 15;          // coalesced along the row
    int r = i >> 4;
    int row = row0 + r;
    float4 v = (row < NN) ? ((const float4*)X)[row * (FI / 4) + c4]
                          : make_float4(0.f, 0.f, 0.f, 0.f);
    XsT[c4 * 4 + 0][r] = v.x; XsT[c4 * 4 + 1][r] = v.y;
    XsT[c4 * 4 + 2][r] = v.z; XsT[c4 * 4 + 3][r] = v.w;
  }
  __syncthreads();

  int tr = tid & 15;   // row group: rows tr*4..+3
  int tc = tid >> 4;   // col group: cols tc*8..+7
  float acc[4][8];
#pragma unroll
  for (int i = 0; i < 4; i++)
#pragma unroll
    for (int j = 0; j < 8; j++) acc[i][j] = 0.f;

#pragma unroll 8
  for (int k = 0; k < FI; k++) {
    float4 a = *(const float4*)&XsT[k][tr * 4];
    float4 w0 = *(const float4*)&Ws[k][tc * 8];
    float4 w1 = *(const float4*)&Ws[k][tc * 8 + 4];
    float av[4] = {a.x, a.y, a.z, a.w};
    float wv[8] = {w0.x, w0.y, w0.z, w0.w, w1.x, w1.y, w1.z, w1.w};
#pragma unroll
    for (int i = 0; i < 4; i++)
#pragma unroll
      for (int j = 0; j < 8; j++) acc[i][j] += av[i] * wv[j];
  }

  float4 bv0 = *(const float4*)&bias[tc * 8];
  float4 bv1 = *(const float4*)&bias[tc * 8 + 4];
  float bb[8] = {bv0.x, bv0.y, bv0.z, bv0.w, bv1.x, bv1.y, bv1.z, bv1.w};
#pragma unroll
  for (int i = 0; i < 4; i++) {
    int row = row0 + tr * 4 + i;
    if (row < NN) {
      float o[8];
#pragma unroll
      for (int j = 0; j < 8; j++) {
        float v = acc[i][j] + bb[j];
        o[j] = v > 0.f ? v : 0.f;
      }
      float4* dst = (float4*)&Y[row * FH + tc * 8];
      dst[0] = make_float4(o[0], o[1], o[2], o[3]);
      dst[1] = make_float4(o[4], o[5], o[6], o[7]);
    }
  }
}

// ---------------- GEMM2: h2 = h1 @ W2   [N,128]@[128,64] (no bias) ----------
// block: 64 rows x 64 cols, 256 threads, thread tile 4x4
__global__ __launch_bounds__(256) void k_gemm2(const float* __restrict__ X,
                                               const float* __restrict__ W,
                                               float* __restrict__ Y) {
  __shared__ float XsT[FH][64];   // 32KB
  __shared__ float Ws[FH][FO];    // 32KB -> total exactly 64KB
  int tid = threadIdx.x;
  int row0 = blockIdx.x * 64;

  for (int i = tid; i < FH * FO / 4; i += 256)
    ((float4*)&Ws[0][0])[i] = ((const float4*)W)[i];

  for (int i = tid; i < 64 * (FH / 4); i += 256) {  // 2048 float4 loads
    int c4 = i & 31;          // coalesced along the row
    int r = i >> 5;
    int row = row0 + r;
    float4 v = (row < NN) ? ((const float4*)X)[row * (FH / 4) + c4]
                          : make_float4(0.f, 0.f, 0.f, 0.f);
    XsT[c4 * 4 + 0][r] = v.x; XsT[c4 * 4 + 1][r] = v.y;
    XsT[c4 * 4 + 2][r] = v.z; XsT[c4 * 4 + 3][r] = v.w;
  }
  __syncthreads();

  int tr = tid & 15;   // rows tr*4..+3
  int tc = tid >> 4;   // cols tc*4..+3
  float acc[4][4];
#pragma unroll
  for (int i = 0; i < 4; i++)
#pragma unroll
    for (int j = 0; j < 4; j++) acc[i][j] = 0.f;

#pragma unroll 8
  for (int k = 0; k < FH; k++) {
    float4 a = *(const float4*)&XsT[k][tr * 4];
    float4 w = *(const float4*)&Ws[k][tc * 4];
    float av[4] = {a.x, a.y, a.z, a.w};
    float wv[4] = {w.x, w.y, w.z, w.w};
#pragma unroll
    for (int i = 0; i < 4; i++)
#pragma unroll
      for (int j = 0; j < 4; j++) acc[i][j] += av[i] * wv[j];
  }

#pragma unroll
  for (int i = 0; i < 4; i++) {
    int row = row0 + tr * 4 + i;
    if (row < NN) {
      *(float4*)&Y[row * FO + tc * 4] =
          make_float4(acc[i][0], acc[i][1], acc[i][2], acc[i][3]);
    }
  }
}

// ---------------- node counts per graph: binary search on SORTED batch ------
// cnts[b] = lower_bound(batch, b+1) - lower_bound(batch, b). No atomics.
__global__ __launch_bounds__(128) void k_cnt_bs(const int* __restrict__ batch,
                                                float* __restrict__ cnts) {
  __shared__ int lb[NB + 1];
  int b = threadIdx.x;
  if (b <= NB) {
    int lo = 0, hi = NN;
    while (lo < hi) {
      int mid = (lo + hi) >> 1;
      if (batch[mid] < b) lo = mid + 1; else hi = mid;
    }
    lb[b] = lo;
  }
  __syncthreads();
  if (b < NB) cnts[b] = (float)(lb[b + 1] - lb[b]);
}

// ---------------- layer2 aggregation fused with pooling ---------------------
// out_sums[batch[dst]] += h2[src]*norm over all edges + self-loops.
// LDS accumulator [64 graphs x 64 feats] per block, merged atomically.
__global__ __launch_bounds__(256) void k_out_edges(const int* __restrict__ es,
                                                   const int* __restrict__ ed,
                                                   const int* __restrict__ batch,
                                                   const float* __restrict__ dinv,
                                                   const float* __restrict__ h2,
                                                   float* __restrict__ out_sums) {
  __shared__ float lds[NB * FO];  // 16KB
  for (int i = threadIdx.x; i < NB * FO; i += 256) lds[i] = 0.f;
  __syncthreads();

  int lane = threadIdx.x & 63;
  int wid = (blockIdx.x * 256 + threadIdx.x) >> 6;
  int nw = (gridDim.x * 256) >> 6;
  const int total = NE + NN;  // real edges + self-loops
  for (int e = wid; e < total; e += nw) {
    int e0 = __builtin_amdgcn_readfirstlane(e);
    int s, d;
    float nrm;
    if (e0 < NE) {
      s = es[e0];
      d = ed[e0];
      nrm = dinv[s] * dinv[d];
    } else {
      s = e0 - NE;
      d = s;
      float di = dinv[s];
      nrm = di * di;
    }
    int b = batch[d];
    atomicAdd(&lds[b * FO + lane], h2[s * FO + lane] * nrm);
  }
  __syncthreads();
  for (int i = threadIdx.x; i < NB * FO; i += 256) {
    float v = lds[i];
    if (v != 0.f) atomicAdd(&out_sums[i], v);
  }
}

// ---------------- final: mean + bias ----------------------------------------
__global__ __launch_bounds__(256) void k_final(const float* __restrict__ out_sums,
                                               const float* __restrict__ cnts,
                                               const float* __restrict__ b2,
                                               float* __restrict__ out) {
  int i = blockIdx.x * 256 + threadIdx.x;
  if (i < NB * FO) {
    int b = i >> 6, j = i & 63;
    out[i] = out_sums[i] / fmaxf(cnts[b], 1.0f) + b2[j];
  }
}

extern "C" void kernel_launch(void* const* d_in, const int* in_sizes, int n_in,
                              void* d_out, int out_size, void* d_ws, size_t ws_size,
                              hipStream_t stream) {
  const float* x = (const float*)d_in[0];
  const int* ei = (const int*)d_in[1];     // [2,E] int32
  const int* batch = (const int*)d_in[2];  // [N] int32
  const float* W1 = (const float*)d_in[3];
  const float* b1 = (const float*)d_in[4];
  const float* W2 = (const float*)d_in[5];
  const float* b2 = (const float*)d_in[6];
  float* out = (float*)d_out;

  const int* es = ei;       // edge_index[0] = src
  const int* ed = ei + NE;  // edge_index[1] = dst

  // workspace layout (f32): deg/dinv | aggx (reused as h2) | h1 | out_sums | cnts
  float* deg = (float*)d_ws;            // N (in-place -> dinv)
  float* aggx = deg + 100032;           // N*64  (25.6MB)
  float* h1 = aggx + (size_t)NN * FI;   // N*128 (51.2MB)
  float* out_sums = h1 + (size_t)NN * FH;
  float* cnts = out_sums + NB * FO;
  float* h2 = aggx;                     // aggx dead after gemm1

  k_init<<<(NN + 255) / 256, 256, 0, stream>>>(deg, out_sums);
  k_deg<<<1024, 256, 0, stream>>>(ed, deg);
  k_dinv<<<(NN + 255) / 256, 256, 0, stream>>>(deg);
  k_aggx_init<<<(NN * (FI / 4) + 255) / 256, 256, 0, stream>>>(x, deg, aggx);
  k_aggx_edges<<<2048, 256, 0, stream>>>(es, ed, deg, x, aggx);
  k_gemm1<<<(NN + 63) / 64, 256, 0, stream>>>(aggx, W1, b1, h1);
  k_gemm2<<<(NN + 63) / 64, 256, 0, stream>>>(h1, W2, h2);
  k_cnt_bs<<<1, 128, 0, stream>>>(batch, cnts);
  k_out_edges<<<1024, 256, 0, stream>>>(es, ed, batch, deg, h2, out_sums);
  k_final<<<16, 256, 0, stream>>>(out_sums, cnts, b2, out);
}

// Round 6
// 1128.909 us; speedup vs baseline: 1.5822x; 1.0299x over previous
//
#include <hip/hip_runtime.h>

// GCN encoder: 2x GCNConv (symmetric norm, self-loops) + global mean pool.
// N=100000 nodes, E=1600000 edges, F_IN=64, H=128, O=64, B=64 graphs.
//
// Algebraic restructure:
//   layer1: h1 = relu((A x) W1 + b1)         (aggregate 64-wide x, then GEMM)
//   layer2+pool: out[b] = (1/cnt[b]) * sum_{edges e: batch[dst]=b} h2[src]*norm + b2
//            where h2 = h1 W2                 (pool fused into edge pass)
//
// R3: k_cnt atomics -> binary search on sorted batch (-623us, matched pred).
// R5: edge passes were latency-bound (MLP=1: one dependent 256B gather per
//     wave-iter; occupancy 48%). Now 4 edges/wave-iter (int4 index loads,
//     4 independent gathers in flight) + 8192 waves (100% occupancy).

#define NN 100000
#define NE 1600000
#define FI 64
#define FH 128
#define FO 64
#define NB 64

// ---------------- init: deg=1 (self-loop), zero pooled sums ----------------
__global__ __launch_bounds__(256) void k_init(float* __restrict__ deg,
                                              float* __restrict__ out_sums) {
  int i = blockIdx.x * 256 + threadIdx.x;
  if (i < NN) deg[i] = 1.0f;
  if (i < NB * FO) out_sums[i] = 0.0f;
}

// ---------------- degree count over dst -------------------------------------
__global__ __launch_bounds__(256) void k_deg(const int* __restrict__ dst,
                                             float* __restrict__ deg) {
  int stride = gridDim.x * 256;
  for (int e = blockIdx.x * 256 + threadIdx.x; e < NE; e += stride)
    atomicAdd(&deg[dst[e]], 1.0f);
}

// ---------------- dinv = rsqrt(deg)  (deg >= 1 always, self-loop) -----------
__global__ __launch_bounds__(256) void k_dinv(float* __restrict__ deg) {
  int i = blockIdx.x * 256 + threadIdx.x;
  if (i < NN) deg[i] = rsqrtf(deg[i]);
}

// ---------------- aggx init with self-loop: aggx[i] = x[i]*dinv[i]^2 --------
__global__ __launch_bounds__(256) void k_aggx_init(const float* __restrict__ x,
                                                   const float* __restrict__ dinv,
                                                   float* __restrict__ aggx) {
  int i = blockIdx.x * 256 + threadIdx.x;  // float4 index
  if (i < NN * (FI / 4)) {
    int node = i >> 4;  // FI/4 = 16 float4 per row
    float di = dinv[node];
    float s = di * di;
    float4 v = ((const float4*)x)[i];
    v.x *= s; v.y *= s; v.z *= s; v.w *= s;
    ((float4*)aggx)[i] = v;
  }
}

// ---------------- edge scatter: aggx[dst] += x[src]*norm --------------------
// 4 edges per wave-iteration: int4 index loads (wave-uniform), 4 independent
// 256B gathers in flight, 4 fire-and-forget global atomic scatters.
__global__ __launch_bounds__(256) void k_aggx_edges(const int* __restrict__ es,
                                                    const int* __restrict__ ed,
                                                    const float* __restrict__ dinv,
                                                    const float* __restrict__ x,
                                                    float* __restrict__ aggx) {
  int lane = threadIdx.x & 63;
  int wid = (blockIdx.x * 256 + threadIdx.x) >> 6;
  int nw = (gridDim.x * 256) >> 6;
  const int nchunk = NE / 4;  // 400000 exactly
  for (int c = wid; c < nchunk; c += nw) {
    int e0 = __builtin_amdgcn_readfirstlane(c * 4);
    int4 sv = *(const int4*)(es + e0);
    int4 dv = *(const int4*)(ed + e0);
    float n0 = dinv[sv.x] * dinv[dv.x];
    float n1 = dinv[sv.y] * dinv[dv.y];
    float n2 = dinv[sv.z] * dinv[dv.z];
    float n3 = dinv[sv.w] * dinv[dv.w];
    float g0 = x[sv.x * FI + lane];
    float g1 = x[sv.y * FI + lane];
    float g2 = x[sv.z * FI + lane];
    float g3 = x[sv.w * FI + lane];
    atomicAdd(&aggx[dv.x * FI + lane], g0 * n0);
    atomicAdd(&aggx[dv.y * FI + lane], g1 * n1);
    atomicAdd(&aggx[dv.z * FI + lane], g2 * n2);
    atomicAdd(&aggx[dv.w * FI + lane], g3 * n3);
  }
}

// ---------------- GEMM1: h1 = relu(aggx @ W1 + b1)   [N,64]@[64,128] --------
// block: 64 rows x 128 cols, 256 threads, thread tile 4x8
__global__ __launch_bounds__(256) void k_gemm1(const float* __restrict__ X,
                                               const float* __restrict__ W,
                                               const float* __restrict__ bias,
                                               float* __restrict__ Y) {
  __shared__ float XsT[FI][64];   // [k][r] transposed, 16KB
  __shared__ float Ws[FI][FH];    // 32KB
  int tid = threadIdx.x;
  int row0 = blockIdx.x * 64;

  for (int i = tid; i < FI * FH / 4; i += 256)
    ((float4*)&Ws[0][0])[i] = ((const float4*)W)[i];

  for (int i = tid; i < 64 * (FI / 4); i += 256) {  // 1024 float4 loads
    int c4 = i & 15;          // coalesced along the row
    int r = i >> 4;
    int row = row0 + r;
    float4 v = (row < NN) ? ((const float4*)X)[row * (FI / 4) + c4]
                          : make_float4(0.f, 0.f, 0.f, 0.f);
    XsT[c4 * 4 + 0][r] = v.x; XsT[c4 * 4 + 1][r] = v.y;
    XsT[c4 * 4 + 2][r] = v.z; XsT[c4 * 4 + 3][r] = v.w;
  }
  __syncthreads();

  int tr = tid & 15;   // row group: rows tr*4..+3
  int tc = tid >> 4;   // col group: cols tc*8..+7
  float acc[4][8];
#pragma unroll
  for (int i = 0; i < 4; i++)
#pragma unroll
    for (int j = 0; j < 8; j++) acc[i][j] = 0.f;

#pragma unroll 8
  for (int k = 0; k < FI; k++) {
    float4 a = *(const float4*)&XsT[k][tr * 4];
    float4 w0 = *(const float4*)&Ws[k][tc * 8];
    float4 w1 = *(const float4*)&Ws[k][tc * 8 + 4];
    float av[4] = {a.x, a.y, a.z, a.w};
    float wv[8] = {w0.x, w0.y, w0.z, w0.w, w1.x, w1.y, w1.z, w1.w};
#pragma unroll
    for (int i = 0; i < 4; i++)
#pragma unroll
      for (int j = 0; j < 8; j++) acc[i][j] += av[i] * wv[j];
  }

  float4 bv0 = *(const float4*)&bias[tc * 8];
  float4 bv1 = *(const float4*)&bias[tc * 8 + 4];
  float bb[8] = {bv0.x, bv0.y, bv0.z, bv0.w, bv1.x, bv1.y, bv1.z, bv1.w};
#pragma unroll
  for (int i = 0; i < 4; i++) {
    int row = row0 + tr * 4 + i;
    if (row < NN) {
      float o[8];
#pragma unroll
      for (int j = 0; j < 8; j++) {
        float v = acc[i][j] + bb[j];
        o[j] = v > 0.f ? v : 0.f;
      }
      float4* dst = (float4*)&Y[row * FH + tc * 8];
      dst[0] = make_float4(o[0], o[1], o[2], o[3]);
      dst[1] = make_float4(o[4], o[5], o[6], o[7]);
    }
  }
}

// ---------------- GEMM2: h2 = h1 @ W2   [N,128]@[128,64] (no bias) ----------
// block: 64 rows x 64 cols, 256 threads, thread tile 4x4
__global__ __launch_bounds__(256) void k_gemm2(const float* __restrict__ X,
                                               const float* __restrict__ W,
                                               float* __restrict__ Y) {
  __shared__ float XsT[FH][64];   // 32KB
  __shared__ float Ws[FH][FO];    // 32KB -> total exactly 64KB
  int tid = threadIdx.x;
  int row0 = blockIdx.x * 64;

  for (int i = tid; i < FH * FO / 4; i += 256)
    ((float4*)&Ws[0][0])[i] = ((const float4*)W)[i];

  for (int i = tid; i < 64 * (FH / 4); i += 256) {  // 2048 float4 loads
    int c4 = i & 31;          // coalesced along the row
    int r = i >> 5;
    int row = row0 + r;
    float4 v = (row < NN) ? ((const float4*)X)[row * (FH / 4) + c4]
                          : make_float4(0.f, 0.f, 0.f, 0.f);
    XsT[c4 * 4 + 0][r] = v.x; XsT[c4 * 4 + 1][r] = v.y;
    XsT[c4 * 4 + 2][r] = v.z; XsT[c4 * 4 + 3][r] = v.w;
  }
  __syncthreads();

  int tr = tid & 15;   // rows tr*4..+3
  int tc = tid >> 4;   // cols tc*4..+3
  float acc[4][4];
#pragma unroll
  for (int i = 0; i < 4; i++)
#pragma unroll
    for (int j = 0; j < 4; j++) acc[i][j] = 0.f;

#pragma unroll 8
  for (int k = 0; k < FH; k++) {
    float4 a = *(const float4*)&XsT[k][tr * 4];
    float4 w = *(const float4*)&Ws[k][tc * 4];
    float av[4] = {a.x, a.y, a.z, a.w};
    float wv[4] = {w.x, w.y, w.z, w.w};
#pragma unroll
    for (int i = 0; i < 4; i++)
#pragma unroll
      for (int j = 0; j < 4; j++) acc[i][j] += av[i] * wv[j];
  }

#pragma unroll
  for (int i = 0; i < 4; i++) {
    int row = row0 + tr * 4 + i;
    if (row < NN) {
      *(float4*)&Y[row * FO + tc * 4] =
          make_float4(acc[i][0], acc[i][1], acc[i][2], acc[i][3]);
    }
  }
}

// ---------------- node counts per graph: binary search on SORTED batch ------
__global__ __launch_bounds__(128) void k_cnt_bs(const int* __restrict__ batch,
                                                float* __restrict__ cnts) {
  __shared__ int lb[NB + 1];
  int b = threadIdx.x;
  if (b <= NB) {
    int lo = 0, hi = NN;
    while (lo < hi) {
      int mid = (lo + hi) >> 1;
      if (batch[mid] < b) lo = mid + 1; else hi = mid;
    }
    lb[b] = lo;
  }
  __syncthreads();
  if (b < NB) cnts[b] = (float)(lb[b + 1] - lb[b]);
}

// ---------------- layer2 aggregation fused with pooling ---------------------
// 4 edges per wave-iteration into LDS [64 graphs x 64 feats]; NE%4==0 so the
// self-loop region (chunks >= NE/4) never mixes with real edges.
__global__ __launch_bounds__(512) void k_out_edges(const int* __restrict__ es,
                                                   const int* __restrict__ ed,
                                                   const int* __restrict__ batch,
                                                   const float* __restrict__ dinv,
                                                   const float* __restrict__ h2,
                                                   float* __restrict__ out_sums) {
  __shared__ float lds[NB * FO];  // 16KB -> 4 blocks/CU, 32 waves/CU
  for (int i = threadIdx.x; i < NB * FO; i += 512) lds[i] = 0.f;
  __syncthreads();

  int lane = threadIdx.x & 63;
  int wid = (blockIdx.x * 512 + threadIdx.x) >> 6;
  int nw = (gridDim.x * 512) >> 6;
  const int nchunk = (NE + NN) / 4;  // 425000 exactly
  for (int c = wid; c < nchunk; c += nw) {
    int e0 = __builtin_amdgcn_readfirstlane(c * 4);
    int s0, s1, s2, s3, b0, b1, b2, b3;
    float n0, n1, n2, n3;
    if (e0 < NE) {
      int4 sv = *(const int4*)(es + e0);
      int4 dv = *(const int4*)(ed + e0);
      s0 = sv.x; s1 = sv.y; s2 = sv.z; s3 = sv.w;
      n0 = dinv[s0] * dinv[dv.x];
      n1 = dinv[s1] * dinv[dv.y];
      n2 = dinv[s2] * dinv[dv.z];
      n3 = dinv[s3] * dinv[dv.w];
      b0 = batch[dv.x]; b1 = batch[dv.y]; b2 = batch[dv.z]; b3 = batch[dv.w];
    } else {
      s0 = e0 - NE; s1 = s0 + 1; s2 = s0 + 2; s3 = s0 + 3;
      float q0 = dinv[s0], q1 = dinv[s1], q2 = dinv[s2], q3 = dinv[s3];
      n0 = q0 * q0; n1 = q1 * q1; n2 = q2 * q2; n3 = q3 * q3;
      b0 = batch[s0]; b1 = batch[s1]; b2 = batch[s2]; b3 = batch[s3];
    }
    float g0 = h2[s0 * FO + lane];
    float g1 = h2[s1 * FO + lane];
    float g2 = h2[s2 * FO + lane];
    float g3 = h2[s3 * FO + lane];
    atomicAdd(&lds[b0 * FO + lane], g0 * n0);
    atomicAdd(&lds[b1 * FO + lane], g1 * n1);
    atomicAdd(&lds[b2 * FO + lane], g2 * n2);
    atomicAdd(&lds[b3 * FO + lane], g3 * n3);
  }
  __syncthreads();
  for (int i = threadIdx.x; i < NB * FO; i += 512) {
    float v = lds[i];
    if (v != 0.f) atomicAdd(&out_sums[i], v);
  }
}

// ---------------- final: mean + bias ----------------------------------------
__global__ __launch_bounds__(256) void k_final(const float* __restrict__ out_sums,
                                               const float* __restrict__ cnts,
                                               const float* __restrict__ b2,
                                               float* __restrict__ out) {
  int i = blockIdx.x * 256 + threadIdx.x;
  if (i < NB * FO) {
    int b = i >> 6, j = i & 63;
    out[i] = out_sums[i] / fmaxf(cnts[b], 1.0f) + b2[j];
  }
}

extern "C" void kernel_launch(void* const* d_in, const int* in_sizes, int n_in,
                              void* d_out, int out_size, void* d_ws, size_t ws_size,
                              hipStream_t stream) {
  const float* x = (const float*)d_in[0];
  const int* ei = (const int*)d_in[1];     // [2,E] int32
  const int* batch = (const int*)d_in[2];  // [N] int32
  const float* W1 = (const float*)d_in[3];
  const float* b1 = (const float*)d_in[4];
  const float* W2 = (const float*)d_in[5];
  const float* b2 = (const float*)d_in[6];
  float* out = (float*)d_out;

  const int* es = ei;       // edge_index[0] = src
  const int* ed = ei + NE;  // edge_index[1] = dst

  // workspace layout (f32): deg/dinv | aggx (reused as h2) | h1 | out_sums | cnts
  float* deg = (float*)d_ws;            // N (in-place -> dinv)
  float* aggx = deg + 100032;           // N*64  (25.6MB)
  float* h1 = aggx + (size_t)NN * FI;   // N*128 (51.2MB)
  float* out_sums = h1 + (size_t)NN * FH;
  float* cnts = out_sums + NB * FO;
  float* h2 = aggx;                     // aggx dead after gemm1

  k_init<<<(NN + 255) / 256, 256, 0, stream>>>(deg, out_sums);
  k_deg<<<1024, 256, 0, stream>>>(ed, deg);
  k_dinv<<<(NN + 255) / 256, 256, 0, stream>>>(deg);
  k_aggx_init<<<(NN * (FI / 4) + 255) / 256, 256, 0, stream>>>(x, deg, aggx);
  k_aggx_edges<<<2048, 256, 0, stream>>>(es, ed, deg, x, aggx);
  k_gemm1<<<(NN + 63) / 64, 256, 0, stream>>>(aggx, W1, b1, h1);
  k_gemm2<<<(NN + 63) / 64, 256, 0, stream>>>(h1, W2, h2);
  k_cnt_bs<<<1, 128, 0, stream>>>(batch, cnts);
  k_out_edges<<<1024, 512, 0, stream>>>(es, ed, batch, deg, h2, out_sums);
  k_final<<<16, 256, 0, stream>>>(out_sums, cnts, b2, out);
}